// Round 7
// baseline (89.990 us; speedup 1.0000x reference)
//
#include <hip/hip_runtime.h>

// SuperPointMatchesGenerator: B=8, N0=N1=2048 mutual-NN under homography.
// d_out f32, concat: gt_matches0[8,2048] | gt_matches1[8,2048] | min_dist0[8,2048]
//
// R7 vs R6 (dur 84.1us; main kernel ~30us of it; ~45-50us is harness poison
// of the 256MB ws + restores, immovable):
//  DEDUP: compute each d2(i,j) ONCE (reference computes `err` once and argmins
//  both axes; both of R6's modes were bit-identical anyway by IEEE add
//  commutativity). Row argmin in-register as before; column argmin via
//  per-(block,candidate) partial over the block's 16 rows + device atomicMin
//  on u64 key (d2bits<<32 | row_in_batch) -> exact keep-smallest-row ties.
//  Op shave: rx2=2*rx, ry2=2*ry precomputed per row. Doubling is exact and
//  distributes over rounding (no overflow/subnormal in range), so
//  fadd(fmul(2rx,cx), fmul(2ry,cy)) == fmul(2, fadd(fmul(rx,cx),fmul(ry,cy)))
//  bit-exactly -> d2 identical to the reference expression.
//  Per unique pair: 6 arith + 3 row-sel + 3 col-sel = 12 ops (was 2x9=18).
//
// FP exactness vs numpy-f32 (no FMA contraction, explicit __f*_rn):
//   p_i = (H[i0]*x + H[i1]*y) + H[i2];  X = p0/(p2+1e-8);  a2 = X*X + Y*Y;
//   d2  = (a2 + b2) - 2*ab;  compare max(d2,0); winner e = sqrt(max(d2,0)).
// Keep-first argmin semantics preserved at every level (strict <, ascending
// iteration order, packed-u64 min with index in low bits).
//
// ws (full path, 672KB): q0 f4[16K] | q1 f4[16K] | colkeys u64[16K] | gt0p u16[16K]
// colkeys initialized to ~0 in prep (NOT relying on the 0xAA poison).
// Fallback (ws < 672KB): R5/R6-proven dual-mode brute force in 64KB.

#define SPN 2048
#define SPT 16384
#define RPB 16   // rows per block (dedup kernel)

__device__ __forceinline__ void sp_reproject(const float* __restrict__ T, int b,
                                             float x, float y,
                                             float& X, float& Y, float& S) {
  const float* H = T + b * 9;
  float p0 = __fadd_rn(__fadd_rn(__fmul_rn(H[0], x), __fmul_rn(H[1], y)), H[2]);
  float p1 = __fadd_rn(__fadd_rn(__fmul_rn(H[3], x), __fmul_rn(H[4], y)), H[5]);
  float p2 = __fadd_rn(__fadd_rn(__fmul_rn(H[6], x), __fmul_rn(H[7], y)), H[8]);
  float den = __fadd_rn(p2, 1e-8f);
  X = __fdiv_rn(p0, den);
  Y = __fdiv_rn(p1, den);
  S = __fadd_rn(__fmul_rn(X, X), __fmul_rn(Y, Y));
}

__global__ __launch_bounds__(256) void sp_prep(
    const float2* __restrict__ k0, const float2* __restrict__ k1,
    const float* __restrict__ T, float4* __restrict__ q0, float4* __restrict__ q1,
    unsigned long long* __restrict__ colkeys) {
  int t = blockIdx.x * 256 + threadIdx.x;
  if (t < SPT) {
    float2 p = k0[t];
    float X, Y, S;
    sp_reproject(T, t >> 11, p.x, p.y, X, Y, S);
    q0[t] = make_float4(X, Y, S, 0.0f);
    colkeys[t] = ~0ull;
  } else {
    int u = t - SPT;
    float2 p = k1[u];
    float S = __fadd_rn(__fmul_rn(p.x, p.x), __fmul_rn(p.y, p.y));
    q1[u] = make_float4(p.x, p.y, S, 0.0f);
  }
}

// Dedup main: 1024 blocks, each = 16 rows (kpts0') x 2048 candidates (kpts1).
// Row argmin -> gt0p/mind. Column partial argmin -> atomicMin(colkeys).
__global__ __launch_bounds__(256) void SuperPointMatchesGenerator_56925496541369_kernel(
    const float4* __restrict__ q0, const float4* __restrict__ q1,
    unsigned short* __restrict__ gt0p, unsigned long long* __restrict__ colkeys,
    float* __restrict__ out_mind) {
  const int base = blockIdx.x * RPB;         // global row start
  const int b = base >> 11, cb = b << 11;
  const int base_ib = base & 2047;           // in-batch row start

  float rx2[RPB], ry2[RPB], rs[RPB], bv[RPB];
  int bi[RPB];
#pragma unroll
  for (int r = 0; r < RPB; r++) {
    float4 v = q0[base + r];
    rx2[r] = __fadd_rn(v.x, v.x);            // exact doubling
    ry2[r] = __fadd_rn(v.y, v.y);
    rs[r] = v.z;
    bv[r] = INFINITY; bi[r] = 0;
  }

#pragma unroll 2
  for (int c = threadIdx.x; c < SPN; c += 256) {
    float4 v = q1[cb + c];
    float cbv = INFINITY;
    int cbr = 0;
#pragma unroll
    for (int r = 0; r < RPB; r++) {
      float ab2 = __fadd_rn(__fmul_rn(rx2[r], v.x), __fmul_rn(ry2[r], v.y));
      float d2 = __fsub_rn(__fadd_rn(rs[r], v.z), ab2);
      float dm = fmaxf(d2, 0.0f);
      if (dm < bv[r]) { bv[r] = dm; bi[r] = c; }   // row argmin (keep-first in c)
      if (dm < cbv)   { cbv = dm; cbr = r; }       // col partial (keep-first in r)
    }
    unsigned long long ck =
        ((unsigned long long)__float_as_uint(cbv) << 32) | (unsigned)(base_ib + cbr);
    atomicMin(&colkeys[cb + c], ck);               // device-scope u64 min
  }

  // row-argmin block reduction (u64 packed, keep smallest candidate on ties)
  unsigned long long key[RPB];
#pragma unroll
  for (int r = 0; r < RPB; r++)
    key[r] = ((unsigned long long)__float_as_uint(bv[r]) << 32) | (unsigned)bi[r];
#pragma unroll
  for (int off = 32; off > 0; off >>= 1) {
#pragma unroll
    for (int r = 0; r < RPB; r++) {
      unsigned long long o = __shfl_down(key[r], off);
      if (o < key[r]) key[r] = o;
    }
  }
  __shared__ unsigned long long part[4][RPB];
  if ((threadIdx.x & 63) == 0) {
    int w = threadIdx.x >> 6;
#pragma unroll
    for (int r = 0; r < RPB; r++) part[w][r] = key[r];
  }
  __syncthreads();
  if (threadIdx.x < RPB) {
    int r = threadIdx.x;
    unsigned long long k = part[0][r];
#pragma unroll
    for (int w = 1; w < 4; w++)
      if (part[w][r] < k) k = part[w][r];
    int idx = (int)(k & 0x7ffu);
    float e = __fsqrt_rn(__uint_as_float((unsigned)(k >> 32)));
    unsigned short pk = (unsigned short)idx;
    if (e > 3.0f) pk |= 0x8000u;                   // strict >, exact fp32
    gt0p[base + r] = pk;
    out_mind[base + r] = e;
  }
}

__global__ __launch_bounds__(256) void SuperPointMatchesGenerator_56925496541369_final(
    const unsigned short* __restrict__ gt0p,
    const unsigned long long* __restrict__ colkeys, float* __restrict__ out) {
  int t = blockIdx.x * 256 + threadIdx.x;
  if (t >= SPT) return;
  int b = t >> 11, i = t & 2047, cb = b << 11;

  unsigned short p0 = gt0p[t];
  int m0 = p0 & 0x7ff;
  int back = (int)(colkeys[cb + m0] & 0x7ffu);
  bool ok0 = ((p0 & 0x8000u) == 0) && (back == i);
  out[t] = ok0 ? (float)m0 : -1.0f;

  int istar = (int)(colkeys[t] & 0x7ffu);          // gather form of the scatter
  unsigned short ps = gt0p[cb + istar];
  bool ok1 = (((int)(ps & 0x7ff)) == i) && ((ps & 0x8000u) == 0);
  out[SPT + t] = ok1 ? (float)istar : -1.0f;
}

// ---------- fallback (R5/R6-proven, 64KB ws) ----------
__global__ __launch_bounds__(256) void sp_fb_main(
    const float2* __restrict__ k0, const float2* __restrict__ k1,
    const float* __restrict__ T, unsigned short* __restrict__ gt0p,
    unsigned short* __restrict__ gt1, float* __restrict__ out_mind) {
  const bool mode1 = blockIdx.x >= SPN;
  const int base = (mode1 ? blockIdx.x - SPN : blockIdx.x) * 8;
  const int b = base >> 11, cb = b << 11;
  float rx[8], ry[8], rs[8], bv[8];
  int bi[8];
#pragma unroll
  for (int r = 0; r < 8; r++) { bv[r] = INFINITY; bi[r] = 0; }
  if (!mode1) {
#pragma unroll
    for (int r = 0; r < 8; r++) {
      float2 p = k0[base + r];
      sp_reproject(T, b, p.x, p.y, rx[r], ry[r], rs[r]);
    }
    for (int c = threadIdx.x; c < SPN; c += 256) {
      float2 p = k1[cb + c];
      float b2 = __fadd_rn(__fmul_rn(p.x, p.x), __fmul_rn(p.y, p.y));
#pragma unroll
      for (int r = 0; r < 8; r++) {
        float ab = __fadd_rn(__fmul_rn(rx[r], p.x), __fmul_rn(ry[r], p.y));
        float d2 = __fsub_rn(__fadd_rn(rs[r], b2), __fmul_rn(2.0f, ab));
        float dm = fmaxf(d2, 0.0f);
        if (dm < bv[r]) { bv[r] = dm; bi[r] = c; }
      }
    }
  } else {
#pragma unroll
    for (int r = 0; r < 8; r++) {
      float2 p = k1[base + r];
      rx[r] = p.x; ry[r] = p.y;
      rs[r] = __fadd_rn(__fmul_rn(p.x, p.x), __fmul_rn(p.y, p.y));
    }
    for (int c = threadIdx.x; c < SPN; c += 256) {
      float2 p = k0[cb + c];
      float cx, cy, a2;
      sp_reproject(T, b, p.x, p.y, cx, cy, a2);
#pragma unroll
      for (int r = 0; r < 8; r++) {
        float ab = __fadd_rn(__fmul_rn(rx[r], cx), __fmul_rn(ry[r], cy));
        float d2 = __fsub_rn(__fadd_rn(a2, rs[r]), __fmul_rn(2.0f, ab));
        float dm = fmaxf(d2, 0.0f);
        if (dm < bv[r]) { bv[r] = dm; bi[r] = c; }
      }
    }
  }
  unsigned long long key[8];
#pragma unroll
  for (int r = 0; r < 8; r++)
    key[r] = ((unsigned long long)__float_as_uint(bv[r]) << 32) | (unsigned)bi[r];
#pragma unroll
  for (int off = 32; off > 0; off >>= 1) {
#pragma unroll
    for (int r = 0; r < 8; r++) {
      unsigned long long o = __shfl_down(key[r], off);
      if (o < key[r]) key[r] = o;
    }
  }
  __shared__ unsigned long long part[4][8];
  if ((threadIdx.x & 63) == 0) {
    int w = threadIdx.x >> 6;
#pragma unroll
    for (int r = 0; r < 8; r++) part[w][r] = key[r];
  }
  __syncthreads();
  if (threadIdx.x < 8) {
    int r = threadIdx.x;
    unsigned long long k = part[0][r];
#pragma unroll
    for (int w = 1; w < 4; w++)
      if (part[w][r] < k) k = part[w][r];
    int idx = (int)(k & 0x7ffu);
    if (!mode1) {
      float e = __fsqrt_rn(__uint_as_float((unsigned)(k >> 32)));
      unsigned short pk = (unsigned short)idx;
      if (e > 3.0f) pk |= 0x8000u;
      gt0p[base + r] = pk;
      out_mind[base + r] = e;
    } else {
      gt1[base + r] = (unsigned short)idx;
    }
  }
}

__global__ __launch_bounds__(256) void sp_fb_final(
    const unsigned short* __restrict__ gt0p, const unsigned short* __restrict__ gt1,
    float* __restrict__ out) {
  int t = blockIdx.x * 256 + threadIdx.x;
  if (t >= SPT) return;
  int b = t >> 11, i = t & 2047, cb = b << 11;
  unsigned short p0 = gt0p[t];
  int m0 = p0 & 0x7ff;
  bool ok0 = ((p0 & 0x8000u) == 0) && ((int)gt1[cb + m0] == i);
  out[t] = ok0 ? (float)m0 : -1.0f;
  int istar = gt1[t];
  unsigned short ps = gt0p[cb + istar];
  bool ok1 = (((int)(ps & 0x7ff)) == i) && ((ps & 0x8000u) == 0);
  out[SPT + t] = ok1 ? (float)istar : -1.0f;
}

extern "C" void kernel_launch(void* const* d_in, const int* in_sizes, int n_in,
                              void* d_out, int out_size, void* d_ws, size_t ws_size,
                              hipStream_t stream) {
  (void)in_sizes; (void)n_in; (void)out_size;
  const float2* k0 = (const float2*)d_in[0];
  const float2* k1 = (const float2*)d_in[1];
  const float* T   = (const float*)d_in[2];
  float* out = (float*)d_out;

  const size_t need = (size_t)2 * SPT * sizeof(float4)
                    + (size_t)SPT * sizeof(unsigned long long)
                    + (size_t)SPT * sizeof(unsigned short);
  if (ws_size >= need) {
    float4* q0 = (float4*)d_ws;                                  // 256 KB
    float4* q1 = q0 + SPT;                                       // 256 KB
    unsigned long long* colkeys = (unsigned long long*)(q1 + SPT);  // 128 KB
    unsigned short* gt0p = (unsigned short*)(colkeys + SPT);        // 32 KB
    sp_prep<<<2 * SPT / 256, 256, 0, stream>>>(k0, k1, T, q0, q1, colkeys);
    SuperPointMatchesGenerator_56925496541369_kernel<<<SPT / RPB, 256, 0, stream>>>(
        q0, q1, gt0p, colkeys, out + 2 * SPT);
    SuperPointMatchesGenerator_56925496541369_final<<<SPT / 256, 256, 0, stream>>>(
        gt0p, colkeys, out);
  } else {
    unsigned short* gt0p = (unsigned short*)d_ws;
    unsigned short* gt1  = gt0p + SPT;
    sp_fb_main<<<2 * SPN, 256, 0, stream>>>(k0, k1, T, gt0p, gt1, out + 2 * SPT);
    sp_fb_final<<<SPT / 256, 256, 0, stream>>>(gt0p, gt1, out);
  }
}